// Round 3
// baseline (444.790 us; speedup 1.0000x reference)
//
#include <hip/hip_runtime.h>
#include <hip/hip_bf16.h>

// ---------------------------------------------------------------------------
// SingleLayerMoE: T=1024 tokens, H=1024, E=8 experts, I=1024, top-2 routing.
// R2: PF2 (2-iteration prefetch distance) + BK=64 + conflict-free B staging +
//     K-split-2 down GEMM. Tiles 128x(32g+32u) / 128x64, 4 waves, 8 MFMA/iter
//     per wave per 32-k substep.
// ---------------------------------------------------------------------------

typedef unsigned short u16;
typedef __attribute__((ext_vector_type(8))) __bf16 bf16x8;
typedef __attribute__((ext_vector_type(4))) float f32x4;

#define T_TOK 1024
#define H_DIM 1024
#define E_NUM 8
#define I_DIM 1024
#define ALPHA 1.702f
#define LIMIT 7.0f
#define LSTR 72          // LDS row stride in u16 (64 data + 8 pad; 36 words: 4*9, 9 coprime 8 -> spread)
#define DPART (2048 * 1024)

// round-to-nearest-even fp32 -> bf16 (no NaN in this workload)
__device__ __forceinline__ u16 f2bf(float f) {
    unsigned u = __builtin_bit_cast(unsigned, f);
    u = (u + 0x7FFFu + ((u >> 16) & 1u)) >> 16;
    return (u16)u;
}

__device__ __forceinline__ f32x4 mfma16(bf16x8 a, bf16x8 b, f32x4 c) {
    return __builtin_amdgcn_mfma_f32_16x16x32_bf16(a, b, c, 0, 0, 0);
}

// --------------------------- K0: zero counters ------------------------------
__global__ void k_zero(int* counts) {
    if (threadIdx.x < E_NUM) counts[threadIdx.x] = 0;
}

// --------------------------- K1: router + dispatch + x->bf16 ----------------
__global__ __launch_bounds__(256) void k_router(
    const float* __restrict__ x, const float* __restrict__ rw,
    const float* __restrict__ rb,
    int* __restrict__ counts, int* __restrict__ tk_e, int* __restrict__ tk_slot,
    float* __restrict__ tk_w, int* __restrict__ tok_list,
    float* __restrict__ w_list, u16* __restrict__ xb)
{
    const int t = blockIdx.x;
    const int tid = threadIdx.x;
    const float4 xv = *(const float4*)(x + (size_t)t * H_DIM + tid * 4);

    unsigned lo = (unsigned)f2bf(xv.x) | ((unsigned)f2bf(xv.y) << 16);
    unsigned hi = (unsigned)f2bf(xv.z) | ((unsigned)f2bf(xv.w) << 16);
    *(uint2*)(xb + (size_t)t * H_DIM + tid * 4) = make_uint2(lo, hi);

    float p[E_NUM];
#pragma unroll
    for (int e = 0; e < E_NUM; ++e) {
        const float4 wv = *(const float4*)(rw + e * H_DIM + tid * 4);
        p[e] = xv.x * wv.x + xv.y * wv.y + xv.z * wv.z + xv.w * wv.w;
    }
#pragma unroll
    for (int off = 32; off; off >>= 1) {
#pragma unroll
        for (int e = 0; e < E_NUM; ++e) p[e] += __shfl_down(p[e], off, 64);
    }
    __shared__ float red[4][E_NUM];
    const int lane = tid & 63, wvid = tid >> 6;
    if (lane == 0) {
#pragma unroll
        for (int e = 0; e < E_NUM; ++e) red[wvid][e] = p[e];
    }
    __syncthreads();
    if (tid == 0) {
        float lg[E_NUM];
#pragma unroll
        for (int e = 0; e < E_NUM; ++e)
            lg[e] = red[0][e] + red[1][e] + red[2][e] + red[3][e] + rb[e];
        float m1 = -1e30f, m2 = -1e30f; int i1 = 0, i2 = 0;
#pragma unroll
        for (int e = 0; e < E_NUM; ++e) {
            float l = lg[e];
            if (l > m1) { m2 = m1; i2 = i1; m1 = l; i1 = e; }
            else if (l > m2) { m2 = l; i2 = e; }
        }
        float s = 0.f;
#pragma unroll
        for (int e = 0; e < E_NUM; ++e) s += __expf(lg[e] - m1);
        const float w0 = 1.0f / s;
        const float w1 = __expf(m2 - m1) / s;
        int ee[2] = { i1, i2 };
        float ww[2] = { w0, w1 };
#pragma unroll
        for (int k = 0; k < 2; ++k) {
            int e = ee[k];
            int slot = atomicAdd(&counts[e], 1);
            tok_list[e * T_TOK + slot] = t;
            w_list[e * T_TOK + slot] = ww[k];
            tk_e[t * 2 + k] = e;
            tk_slot[t * 2 + k] = slot;
            tk_w[t * 2 + k] = ww[k];
        }
    }
}

// --------------------------- K2: prefix over 8 counts -----------------------
__global__ void k_prefix(const int* __restrict__ counts, int* __restrict__ ebase) {
    if (threadIdx.x == 0) {
        int a = 0;
        for (int e = 0; e < E_NUM; ++e) { ebase[e] = a; a += counts[e]; }
    }
}

// --------------------------- K3: gate_up GEMM + GLU -------------------------
// block: 128 rows x (32 gate + 32 up cols), BK=64, PF2.
// grid (32 col-strips, 8 m-tiles, 8 experts); ~512 active blocks.
__global__ __launch_bounds__(256) void k_gateup(
    const float* __restrict__ gup, const float* __restrict__ gub,
    const int* __restrict__ counts, const int* __restrict__ ebase,
    const int* __restrict__ tok_list, const u16* __restrict__ xb,
    u16* __restrict__ act)
{
    const int e = blockIdx.z;
    const int cnt = counts[e];
    const int m0 = blockIdx.y * 128;
    if (m0 >= cnt) return;
    const int n0 = blockIdx.x * 32;
    const int abase = ebase[e];
    const int tid = threadIdx.x;

    __shared__ __align__(16) u16 As[128 * LSTR];          // 18.4 KB
    __shared__ __align__(16) u16 Bs[64 * LSTR];           // 9.2 KB (0..31 gate, 32..63 up)

    // A staging: row = tid>>1, k-half = (tid&1)*32; 4 x uint4 per 64-k chunk
    const int arow_i = tid >> 1, akh = (tid & 1) * 32;
    const int aslot = m0 + arow_i;
    const int atok = (aslot < cnt) ? tok_list[e * T_TOK + aslot] : 0;
    const u16* asrc = xb + (size_t)atok * H_DIM + akh;
    u16* adst = &As[arow_i * LSTR + akh];

    // B staging: cg = tid>>5 (col quad), kk = tid&31 (k row; pairs kk, kk+32).
    // bf16 scalar writes at 144B stride land on banks 16*cg + kk/2: conflict-free.
    const int cg = tid >> 5, kk = tid & 31;
    const float* bgate = gup + ((size_t)e << 21) + n0 + cg * 4;
    const float* bup   = bgate + 1024;

    const int lane = tid & 63, wv = tid >> 6;
    const int fm = lane & 15, kg = lane >> 4;

    f32x4 accg[2][2], accu[2][2];
#pragma unroll
    for (int mt = 0; mt < 2; ++mt)
#pragma unroll
        for (int nt = 0; nt < 2; ++nt) {
            accg[mt][nt] = (f32x4){0.f, 0.f, 0.f, 0.f};
            accu[mt][nt] = (f32x4){0.f, 0.f, 0.f, 0.f};
        }

    uint4  pa[2][4];
    float4 pg[2][2], pu[2][2];

#define GU_ISSUE(CH, S)                                                        \
    {                                                                          \
        const int kb_ = (CH) * 64;                                             \
        pa[S][0] = *(const uint4*)(asrc + kb_);                                \
        pa[S][1] = *(const uint4*)(asrc + kb_ + 8);                            \
        pa[S][2] = *(const uint4*)(asrc + kb_ + 16);                           \
        pa[S][3] = *(const uint4*)(asrc + kb_ + 24);                           \
        pg[S][0] = *(const float4*)(bgate + (size_t)(kb_ + kk) * 2048);        \
        pg[S][1] = *(const float4*)(bgate + (size_t)(kb_ + kk + 32) * 2048);   \
        pu[S][0] = *(const float4*)(bup   + (size_t)(kb_ + kk) * 2048);        \
        pu[S][1] = *(const float4*)(bup   + (size_t)(kb_ + kk + 32) * 2048);   \
    }

    GU_ISSUE(0, 0);
    GU_ISSUE(1, 1);

    for (int it = 0; it < 16; ++it) {
        const int s = it & 1;
        __syncthreads();
        *(uint4*)(adst)      = pa[s][0];
        *(uint4*)(adst + 8)  = pa[s][1];
        *(uint4*)(adst + 16) = pa[s][2];
        *(uint4*)(adst + 24) = pa[s][3];
#pragma unroll
        for (int r2 = 0; r2 < 2; ++r2) {
            const int krow = kk + r2 * 32;
            const float* g = (const float*)&pg[s][r2];
            const float* u = (const float*)&pu[s][r2];
#pragma unroll
            for (int j = 0; j < 4; ++j) {
                Bs[(cg * 4 + j) * LSTR + krow]      = f2bf(g[j]);
                Bs[(32 + cg * 4 + j) * LSTR + krow] = f2bf(u[j]);
            }
        }
        if (it + 2 < 16) { GU_ISSUE(it + 2, s); }
        __syncthreads();

#pragma unroll
        for (int sub = 0; sub < 2; ++sub) {
            bf16x8 af0 = *(const bf16x8*)&As[(wv * 32 + fm) * LSTR + sub * 32 + kg * 8];
            bf16x8 af1 = *(const bf16x8*)&As[(wv * 32 + 16 + fm) * LSTR + sub * 32 + kg * 8];
#pragma unroll
            for (int nt = 0; nt < 2; ++nt) {
                bf16x8 bg = *(const bf16x8*)&Bs[(nt * 16 + fm) * LSTR + sub * 32 + kg * 8];
                bf16x8 bu = *(const bf16x8*)&Bs[(32 + nt * 16 + fm) * LSTR + sub * 32 + kg * 8];
                accg[0][nt] = mfma16(af0, bg, accg[0][nt]);
                accg[1][nt] = mfma16(af1, bg, accg[1][nt]);
                accu[0][nt] = mfma16(af0, bu, accu[0][nt]);
                accu[1][nt] = mfma16(af1, bu, accu[1][nt]);
            }
        }
    }
#undef GU_ISSUE

    // epilogue: bias + clamped GLU, write compact bf16 act rows
#pragma unroll
    for (int mt = 0; mt < 2; ++mt) {
#pragma unroll
        for (int r = 0; r < 4; ++r) {
            int rowb = wv * 32 + mt * 16 + kg * 4 + r;  // C/D: row=(lane>>4)*4+reg
            int slot = m0 + rowb;
            if (slot >= cnt) continue;
            size_t arow_o = (size_t)(abase + slot) * I_DIM;
#pragma unroll
            for (int nt = 0; nt < 2; ++nt) {
                int cn = n0 + nt * 16 + fm;             // C/D: col=lane&15
                float g = accg[mt][nt][r] + gub[e * 2048 + cn];
                float u = accu[mt][nt][r] + gub[e * 2048 + 1024 + cn];
                g = fminf(g, LIMIT);
                u = fminf(fmaxf(u, -LIMIT), LIMIT);
                float glu = g / (1.f + __expf(-ALPHA * g));
                act[arow_o + cn] = f2bf((u + 1.f) * glu);
            }
        }
    }
}

// --------------------------- K4: down GEMM (K-split 2) ----------------------
// block: 128 rows x 64 cols, K range [ks*512, ks*512+512), BK=64, PF2.
// grid (16 col-strips, 8 m-tiles, 8 experts * 2 ksplit); ~1024 active blocks.
__global__ __launch_bounds__(256) void k_down(
    const float* __restrict__ dp,
    const int* __restrict__ counts, const int* __restrict__ ebase,
    const float* __restrict__ w_list,
    const u16* __restrict__ act, float* __restrict__ dout)
{
    const int e = blockIdx.z & 7, ks = blockIdx.z >> 3;
    const int cnt = counts[e];
    const int m0 = blockIdx.y * 128;
    if (m0 >= cnt) return;
    const int n0 = blockIdx.x * 64;
    const int abase = ebase[e];
    const int tid = threadIdx.x;

    __shared__ __align__(16) u16 As[128 * LSTR];
    __shared__ __align__(16) u16 Bs[64 * LSTR];

    const int arow_i = tid >> 1, akh = (tid & 1) * 32;
    const u16* asrc = act + (size_t)(abase + m0 + arow_i) * I_DIM + ks * 512 + akh;
    u16* adst = &As[arow_i * LSTR + akh];

    const int cg = tid >> 5, kk = tid & 31;
    const float* bsrc = dp + ((size_t)e << 20) + (size_t)(ks * 512) * 1024 + n0 + cg * 4;

    const int lane = tid & 63, wv = tid >> 6;
    const int fm = lane & 15, kg = lane >> 4;

    f32x4 acc[2][4];
#pragma unroll
    for (int mt = 0; mt < 2; ++mt)
#pragma unroll
        for (int nt = 0; nt < 4; ++nt) acc[mt][nt] = (f32x4){0.f, 0.f, 0.f, 0.f};

    uint4  pa[2][4];
    float4 pb[2][4];

#define DN_ISSUE(CH, S)                                                        \
    {                                                                          \
        const int kb_ = (CH) * 64;                                             \
        pa[S][0] = *(const uint4*)(asrc + kb_);                                \
        pa[S][1] = *(const uint4*)(asrc + kb_ + 8);                            \
        pa[S][2] = *(const uint4*)(asrc + kb_ + 16);                           \
        pa[S][3] = *(const uint4*)(asrc + kb_ + 24);                           \
        pb[S][0] = *(const float4*)(bsrc + (size_t)(kb_ + kk) * 1024);         \
        pb[S][1] = *(const float4*)(bsrc + (size_t)(kb_ + kk) * 1024 + 32);    \
        pb[S][2] = *(const float4*)(bsrc + (size_t)(kb_ + kk + 32) * 1024);    \
        pb[S][3] = *(const float4*)(bsrc + (size_t)(kb_ + kk + 32) * 1024 + 32);\
    }

    DN_ISSUE(0, 0);
    DN_ISSUE(1, 1);

    for (int it = 0; it < 8; ++it) {
        const int s = it & 1;
        __syncthreads();
        *(uint4*)(adst)      = pa[s][0];
        *(uint4*)(adst + 8)  = pa[s][1];
        *(uint4*)(adst + 16) = pa[s][2];
        *(uint4*)(adst + 24) = pa[s][3];
#pragma unroll
        for (int r2 = 0; r2 < 2; ++r2) {
#pragma unroll
            for (int q = 0; q < 2; ++q) {
                const int krow = kk + r2 * 32;
                const float* b = (const float*)&pb[s][r2 * 2 + q];
#pragma unroll
                for (int j = 0; j < 4; ++j)
                    Bs[(cg * 4 + q * 32 + j) * LSTR + krow] = f2bf(b[j]);
            }
        }
        if (it + 2 < 8) { DN_ISSUE(it + 2, s); }
        __syncthreads();

#pragma unroll
        for (int sub = 0; sub < 2; ++sub) {
            bf16x8 af0 = *(const bf16x8*)&As[(wv * 32 + fm) * LSTR + sub * 32 + kg * 8];
            bf16x8 af1 = *(const bf16x8*)&As[(wv * 32 + 16 + fm) * LSTR + sub * 32 + kg * 8];
#pragma unroll
            for (int nt = 0; nt < 4; ++nt) {
                bf16x8 b = *(const bf16x8*)&Bs[(nt * 16 + fm) * LSTR + sub * 32 + kg * 8];
                acc[0][nt] = mfma16(af0, b, acc[0][nt]);
                acc[1][nt] = mfma16(af1, b, acc[1][nt]);
            }
        }
    }
#undef DN_ISSUE

#pragma unroll
    for (int mt = 0; mt < 2; ++mt) {
#pragma unroll
        for (int r = 0; r < 4; ++r) {
            int rowb = wv * 32 + mt * 16 + kg * 4 + r;
            int slot = m0 + rowb;
            if (slot >= cnt) continue;
            float wgt = w_list[e * T_TOK + slot];
            size_t drow = (size_t)ks * DPART + (size_t)(abase + slot) * H_DIM;
#pragma unroll
            for (int nt = 0; nt < 4; ++nt)
                dout[drow + n0 + nt * 16 + fm] = acc[mt][nt][r] * wgt;
        }
    }
}

// --------------------------- K5: combine pairs + parts + bias ---------------
__global__ __launch_bounds__(256) void k_combine(
    const float* __restrict__ dout, const float* __restrict__ db,
    const int* __restrict__ tk_e, const int* __restrict__ tk_slot,
    const float* __restrict__ tk_w, const int* __restrict__ ebase,
    float* __restrict__ out)
{
    const int t = blockIdx.x, tid = threadIdx.x;
    const int e0 = tk_e[t * 2], e1 = tk_e[t * 2 + 1];
    const size_t p0 = (size_t)(ebase[e0] + tk_slot[t * 2]) * H_DIM;
    const size_t p1 = (size_t)(ebase[e1] + tk_slot[t * 2 + 1]) * H_DIM;
    const float w0 = tk_w[t * 2], w1 = tk_w[t * 2 + 1];
    const int c = tid * 4;
    float4 a0 = *(const float4*)(dout + p0 + c);
    float4 a1 = *(const float4*)(dout + DPART + p0 + c);
    float4 b0 = *(const float4*)(dout + p1 + c);
    float4 b1 = *(const float4*)(dout + DPART + p1 + c);
    float4 d0 = *(const float4*)(db + e0 * H_DIM + c);
    float4 d1 = *(const float4*)(db + e1 * H_DIM + c);
    float4 o;
    o.x = a0.x + a1.x + b0.x + b1.x + w0 * d0.x + w1 * d1.x;
    o.y = a0.y + a1.y + b0.y + b1.y + w0 * d0.y + w1 * d1.y;
    o.z = a0.z + a1.z + b0.z + b1.z + w0 * d0.z + w1 * d1.z;
    o.w = a0.w + a1.w + b0.w + b1.w + w0 * d0.w + w1 * d1.w;
    *(float4*)(out + (size_t)t * H_DIM + c) = o;
}

// ---------------------------------------------------------------------------
extern "C" void kernel_launch(void* const* d_in, const int* in_sizes, int n_in,
                              void* d_out, int out_size, void* d_ws, size_t ws_size,
                              hipStream_t stream) {
    const float* x   = (const float*)d_in[0]; // [1,1024,1024]
    const float* rw  = (const float*)d_in[1]; // [8,1024]
    const float* rb  = (const float*)d_in[2]; // [8]
    const float* gup = (const float*)d_in[3]; // [8,1024,2048]
    const float* gub = (const float*)d_in[4]; // [8,2048]
    const float* dp  = (const float*)d_in[5]; // [8,1024,1024]
    const float* db  = (const float*)d_in[6]; // [8,1024]
    float* out = (float*)d_out;

    char* ws = (char*)d_ws;
    int*   counts   = (int*)(ws);                       // 8 ints
    int*   ebase    = (int*)(ws + 32);                  // 8 ints
    int*   tk_e     = (int*)(ws + 64);                  // 2048 ints
    int*   tk_slot  = (int*)(ws + 64 + 8192);           // 2048 ints
    float* tk_w     = (float*)(ws + 64 + 16384);        // 2048 f32
    int*   tok_list = (int*)(ws + 64 + 24576);          // 8*1024 ints
    float* w_list   = (float*)(ws + 64 + 24576 + 32768);// 8*1024 f32
    u16*   xb       = (u16*)(ws + 90368);               // 1024*1024 bf16 (2 MB)
    u16*   act      = (u16*)(ws + 90368 + 2097152);     // 2048*1024 bf16 (4 MB)
    float* dout     = (float*)(ws + 90368 + 2097152 + 4456448); // 2 x 2048*1024 f32 (16 MB)

    k_zero<<<1, 64, 0, stream>>>(counts);
    k_router<<<T_TOK, 256, 0, stream>>>(x, rw, rb, counts, tk_e, tk_slot, tk_w,
                                        tok_list, w_list, xb);
    k_prefix<<<1, 64, 0, stream>>>(counts, ebase);
    k_gateup<<<dim3(32, 8, 8), 256, 0, stream>>>(gup, gub, counts, ebase,
                                                 tok_list, xb, act);
    k_down<<<dim3(16, 8, 16), 256, 0, stream>>>(dp, counts, ebase, w_list, act, dout);
    k_combine<<<T_TOK, 256, 0, stream>>>(dout, db, tk_e, tk_slot, tk_w, ebase, out);
}

// Round 4
// 219.072 us; speedup vs baseline: 2.0303x; 2.0303x over previous
//
#include <hip/hip_runtime.h>
#include <hip/hip_bf16.h>

// ---------------------------------------------------------------------------
// SingleLayerMoE: T=1024 tokens, H=1024, E=8 experts, I=1024, top-2 routing.
// R3: PF1 prefetch in NAMED registers (R2's dynamic-indexed arrays spilled to
//     scratch: 278 MB write traffic), BK=64, BM=64 tiles -> ~1024 active
//     blocks (4/CU) per GEMM, coalesced 64B B-load runs, LDS stride 72.
// ---------------------------------------------------------------------------

typedef unsigned short u16;
typedef __attribute__((ext_vector_type(8))) __bf16 bf16x8;
typedef __attribute__((ext_vector_type(4))) float f32x4;

#define T_TOK 1024
#define H_DIM 1024
#define E_NUM 8
#define I_DIM 1024
#define ALPHA 1.702f
#define LIMIT 7.0f
#define LSTR 72          // u16 row stride: 36 words -> bank quad = 4*(row+kg) mod 32, uniform 8/quad
#define DPART (2048 * 1024)

__device__ __forceinline__ u16 f2bf(float f) {
    unsigned u = __builtin_bit_cast(unsigned, f);
    u = (u + 0x7FFFu + ((u >> 16) & 1u)) >> 16;
    return (u16)u;
}

__device__ __forceinline__ f32x4 mfma16(bf16x8 a, bf16x8 b, f32x4 c) {
    return __builtin_amdgcn_mfma_f32_16x16x32_bf16(a, b, c, 0, 0, 0);
}

// --------------------------- K0: zero counters ------------------------------
__global__ void k_zero(int* counts) {
    if (threadIdx.x < E_NUM) counts[threadIdx.x] = 0;
}

// --------------------------- K1: router + dispatch + x->bf16 ----------------
__global__ __launch_bounds__(256) void k_router(
    const float* __restrict__ x, const float* __restrict__ rw,
    const float* __restrict__ rb,
    int* __restrict__ counts, int* __restrict__ tk_e, int* __restrict__ tk_slot,
    float* __restrict__ tk_w, int* __restrict__ tok_list,
    float* __restrict__ w_list, u16* __restrict__ xb)
{
    const int t = blockIdx.x;
    const int tid = threadIdx.x;
    const float4 xv = *(const float4*)(x + (size_t)t * H_DIM + tid * 4);

    unsigned lo = (unsigned)f2bf(xv.x) | ((unsigned)f2bf(xv.y) << 16);
    unsigned hi = (unsigned)f2bf(xv.z) | ((unsigned)f2bf(xv.w) << 16);
    *(uint2*)(xb + (size_t)t * H_DIM + tid * 4) = make_uint2(lo, hi);

    float p[E_NUM];
#pragma unroll
    for (int e = 0; e < E_NUM; ++e) {
        const float4 wv = *(const float4*)(rw + e * H_DIM + tid * 4);
        p[e] = xv.x * wv.x + xv.y * wv.y + xv.z * wv.z + xv.w * wv.w;
    }
#pragma unroll
    for (int off = 32; off; off >>= 1) {
#pragma unroll
        for (int e = 0; e < E_NUM; ++e) p[e] += __shfl_down(p[e], off, 64);
    }
    __shared__ float red[4][E_NUM];
    const int lane = tid & 63, wvid = tid >> 6;
    if (lane == 0) {
#pragma unroll
        for (int e = 0; e < E_NUM; ++e) red[wvid][e] = p[e];
    }
    __syncthreads();
    if (tid == 0) {
        float lg[E_NUM];
#pragma unroll
        for (int e = 0; e < E_NUM; ++e)
            lg[e] = red[0][e] + red[1][e] + red[2][e] + red[3][e] + rb[e];
        float m1 = -1e30f, m2 = -1e30f; int i1 = 0, i2 = 0;
#pragma unroll
        for (int e = 0; e < E_NUM; ++e) {
            float l = lg[e];
            if (l > m1) { m2 = m1; i2 = i1; m1 = l; i1 = e; }
            else if (l > m2) { m2 = l; i2 = e; }
        }
        float s = 0.f;
#pragma unroll
        for (int e = 0; e < E_NUM; ++e) s += __expf(lg[e] - m1);
        const float w0 = 1.0f / s;
        const float w1 = __expf(m2 - m1) / s;
        int ee[2] = { i1, i2 };
        float ww[2] = { w0, w1 };
#pragma unroll
        for (int k = 0; k < 2; ++k) {
            int e = ee[k];
            int slot = atomicAdd(&counts[e], 1);
            tok_list[e * T_TOK + slot] = t;
            w_list[e * T_TOK + slot] = ww[k];
            tk_e[t * 2 + k] = e;
            tk_slot[t * 2 + k] = slot;
            tk_w[t * 2 + k] = ww[k];
        }
    }
}

// --------------------------- K2: prefix over 8 counts -----------------------
__global__ void k_prefix(const int* __restrict__ counts, int* __restrict__ ebase) {
    if (threadIdx.x == 0) {
        int a = 0;
        for (int e = 0; e < E_NUM; ++e) { ebase[e] = a; a += counts[e]; }
    }
}

// --------------------------- K3: gate_up GEMM + GLU -------------------------
// tile: 64 rows x (32 gate + 32 up), BK=64; grid (32 strips, 16 m, 8 e).
__global__ __launch_bounds__(256) void k_gateup(
    const float* __restrict__ gup, const float* __restrict__ gub,
    const int* __restrict__ counts, const int* __restrict__ ebase,
    const int* __restrict__ tok_list, const u16* __restrict__ xb,
    u16* __restrict__ act)
{
    const int e = blockIdx.z;
    const int cnt = counts[e];
    const int m0 = blockIdx.y * 64;
    if (m0 >= cnt) return;
    const int n0 = blockIdx.x * 32;
    const int abase = ebase[e];
    const int tid = threadIdx.x;

    __shared__ __align__(16) u16 As[64 * LSTR];   // 9.2 KB
    __shared__ __align__(16) u16 Bs[64 * LSTR];   // rows 0..31 gate, 32..63 up

    // A staging: row = tid>>2, k-quarter = (tid&3)*16 (2 x uint4 per iter)
    const int arow_i = tid >> 2, akq = (tid & 3) * 16;
    const int aslot = m0 + arow_i;
    const int atok = (aslot < cnt) ? tok_list[e * T_TOK + aslot] : 0;
    const u16* asrc = xb + (size_t)atok * H_DIM + akq;
    u16* adst = &As[arow_i * LSTR + akq];

    // B staging: k-row kk = tid>>2, q = tid&3; lanes q=0..3 cover 64B runs
    const int kk = tid >> 2, q = tid & 3;
    const float* bg = gup + ((size_t)e << 21) + n0 + q * 4;
    const float* bu = bg + 1024;

    const int lane = tid & 63, wv = tid >> 6;
    const int fm = lane & 15, kg = lane >> 4;

    f32x4 accg[2], accu[2];
#pragma unroll
    for (int nt = 0; nt < 2; ++nt) {
        accg[nt] = (f32x4){0.f, 0.f, 0.f, 0.f};
        accu[nt] = (f32x4){0.f, 0.f, 0.f, 0.f};
    }

    // PF1 in NAMED registers (no dynamic indexing -> no scratch spill)
    uint4  pa0, pa1;
    float4 pg0, pg1, pu0, pu1;
    {
        pa0 = *(const uint4*)(asrc);
        pa1 = *(const uint4*)(asrc + 8);
        const float* g = bg + (size_t)kk * 2048;
        const float* u = bu + (size_t)kk * 2048;
        pg0 = *(const float4*)(g);      pg1 = *(const float4*)(g + 16);
        pu0 = *(const float4*)(u);      pu1 = *(const float4*)(u + 16);
    }

    for (int kb = 0; kb < H_DIM; kb += 64) {
        __syncthreads();
        *(uint4*)adst       = pa0;
        *(uint4*)(adst + 8) = pa1;
        {
            const float* g0 = (const float*)&pg0; const float* g1 = (const float*)&pg1;
            const float* u0 = (const float*)&pu0; const float* u1 = (const float*)&pu1;
#pragma unroll
            for (int j = 0; j < 4; ++j) {
                Bs[(q * 4 + j) * LSTR + kk]      = f2bf(g0[j]);
                Bs[(16 + q * 4 + j) * LSTR + kk] = f2bf(g1[j]);
                Bs[(32 + q * 4 + j) * LSTR + kk] = f2bf(u0[j]);
                Bs[(48 + q * 4 + j) * LSTR + kk] = f2bf(u1[j]);
            }
        }
        if (kb + 64 < H_DIM) {
            const u16* a = asrc + kb + 64;
            pa0 = *(const uint4*)(a);
            pa1 = *(const uint4*)(a + 8);
            const float* g = bg + (size_t)(kb + 64 + kk) * 2048;
            const float* u = bu + (size_t)(kb + 64 + kk) * 2048;
            pg0 = *(const float4*)(g);      pg1 = *(const float4*)(g + 16);
            pu0 = *(const float4*)(u);      pu1 = *(const float4*)(u + 16);
        }
        __syncthreads();

#pragma unroll
        for (int sub = 0; sub < 2; ++sub) {
            bf16x8 af = *(const bf16x8*)&As[(wv * 16 + fm) * LSTR + sub * 32 + kg * 8];
#pragma unroll
            for (int nt = 0; nt < 2; ++nt) {
                bf16x8 bgf = *(const bf16x8*)&Bs[(nt * 16 + fm) * LSTR + sub * 32 + kg * 8];
                bf16x8 buf = *(const bf16x8*)&Bs[(32 + nt * 16 + fm) * LSTR + sub * 32 + kg * 8];
                accg[nt] = mfma16(af, bgf, accg[nt]);
                accu[nt] = mfma16(af, buf, accu[nt]);
            }
        }
    }

    // epilogue: bias + clamped GLU -> compact bf16 act rows
#pragma unroll
    for (int r = 0; r < 4; ++r) {
        int rowb = wv * 16 + kg * 4 + r;       // C/D: row=(lane>>4)*4+reg
        int slot = m0 + rowb;
        if (slot >= cnt) continue;
        size_t arow_o = (size_t)(abase + slot) * I_DIM;
#pragma unroll
        for (int nt = 0; nt < 2; ++nt) {
            int cn = n0 + nt * 16 + fm;        // C/D: col=lane&15
            float g = accg[nt][r] + gub[e * 2048 + cn];
            float u = accu[nt][r] + gub[e * 2048 + 1024 + cn];
            g = fminf(g, LIMIT);
            u = fminf(fmaxf(u, -LIMIT), LIMIT);
            float glu = g / (1.f + __expf(-ALPHA * g));
            act[arow_o + cn] = f2bf((u + 1.f) * glu);
        }
    }
}

// --------------------------- K4: down GEMM (K-split 2) ----------------------
// tile: 64 rows x 64 cols, K range [ks*512, +512), BK=64;
// grid (16 strips, 16 m, 8 e * 2 ks).
__global__ __launch_bounds__(256) void k_down(
    const float* __restrict__ dp,
    const int* __restrict__ counts, const int* __restrict__ ebase,
    const float* __restrict__ w_list,
    const u16* __restrict__ act, float* __restrict__ dout)
{
    const int e = blockIdx.z & 7, ks = blockIdx.z >> 3;
    const int cnt = counts[e];
    const int m0 = blockIdx.y * 64;
    if (m0 >= cnt) return;
    const int n0 = blockIdx.x * 64;
    const int abase = ebase[e];
    const int tid = threadIdx.x;

    __shared__ __align__(16) u16 As[64 * LSTR];
    __shared__ __align__(16) u16 Bs[64 * LSTR];

    const int arow_i = tid >> 2, akq = (tid & 3) * 16;
    // rows past cnt read adjacent ws rows (finite), masked at store
    const u16* asrc = act + (size_t)(abase + m0 + arow_i) * I_DIM + ks * 512 + akq;
    u16* adst = &As[arow_i * LSTR + akq];

    const int kk = tid >> 2, q = tid & 3;
    const float* bsrc = dp + ((size_t)e << 20) + (size_t)(ks * 512) * 1024 + n0 + q * 4;

    const int lane = tid & 63, wv = tid >> 6;
    const int fm = lane & 15, kg = lane >> 4;

    f32x4 acc[4];
#pragma unroll
    for (int nt = 0; nt < 4; ++nt) acc[nt] = (f32x4){0.f, 0.f, 0.f, 0.f};

    uint4  pa0, pa1;
    float4 pb0, pb1, pb2, pb3;
    {
        pa0 = *(const uint4*)(asrc);
        pa1 = *(const uint4*)(asrc + 8);
        const float* b = bsrc + (size_t)kk * 1024;
        pb0 = *(const float4*)(b);       pb1 = *(const float4*)(b + 16);
        pb2 = *(const float4*)(b + 32);  pb3 = *(const float4*)(b + 48);
    }

    for (int kb = 0; kb < 512; kb += 64) {
        __syncthreads();
        *(uint4*)adst       = pa0;
        *(uint4*)(adst + 8) = pa1;
        {
            const float* b0 = (const float*)&pb0; const float* b1 = (const float*)&pb1;
            const float* b2 = (const float*)&pb2; const float* b3 = (const float*)&pb3;
#pragma unroll
            for (int j = 0; j < 4; ++j) {
                Bs[(q * 4 + j) * LSTR + kk]      = f2bf(b0[j]);
                Bs[(16 + q * 4 + j) * LSTR + kk] = f2bf(b1[j]);
                Bs[(32 + q * 4 + j) * LSTR + kk] = f2bf(b2[j]);
                Bs[(48 + q * 4 + j) * LSTR + kk] = f2bf(b3[j]);
            }
        }
        if (kb + 64 < 512) {
            const u16* a = asrc + kb + 64;
            pa0 = *(const uint4*)(a);
            pa1 = *(const uint4*)(a + 8);
            const float* b = bsrc + (size_t)(kb + 64 + kk) * 1024;
            pb0 = *(const float4*)(b);       pb1 = *(const float4*)(b + 16);
            pb2 = *(const float4*)(b + 32);  pb3 = *(const float4*)(b + 48);
        }
        __syncthreads();

#pragma unroll
        for (int sub = 0; sub < 2; ++sub) {
            bf16x8 af = *(const bf16x8*)&As[(wv * 16 + fm) * LSTR + sub * 32 + kg * 8];
#pragma unroll
            for (int nt = 0; nt < 4; ++nt) {
                bf16x8 b = *(const bf16x8*)&Bs[(nt * 16 + fm) * LSTR + sub * 32 + kg * 8];
                acc[nt] = mfma16(af, b, acc[nt]);
            }
        }
    }

#pragma unroll
    for (int r = 0; r < 4; ++r) {
        int rowb = wv * 16 + kg * 4 + r;
        int slot = m0 + rowb;
        if (slot >= cnt) continue;
        float wgt = w_list[e * T_TOK + slot];
        size_t drow = (size_t)ks * DPART + (size_t)(abase + slot) * H_DIM;
#pragma unroll
        for (int nt = 0; nt < 4; ++nt)
            dout[drow + n0 + nt * 16 + fm] = acc[nt][r] * wgt;
    }
}

// --------------------------- K5: combine pairs + parts + bias ---------------
__global__ __launch_bounds__(256) void k_combine(
    const float* __restrict__ dout, const float* __restrict__ db,
    const int* __restrict__ tk_e, const int* __restrict__ tk_slot,
    const float* __restrict__ tk_w, const int* __restrict__ ebase,
    float* __restrict__ out)
{
    const int t = blockIdx.x, tid = threadIdx.x;
    const int e0 = tk_e[t * 2], e1 = tk_e[t * 2 + 1];
    const size_t p0 = (size_t)(ebase[e0] + tk_slot[t * 2]) * H_DIM;
    const size_t p1 = (size_t)(ebase[e1] + tk_slot[t * 2 + 1]) * H_DIM;
    const float w0 = tk_w[t * 2], w1 = tk_w[t * 2 + 1];
    const int c = tid * 4;
    float4 a0 = *(const float4*)(dout + p0 + c);
    float4 a1 = *(const float4*)(dout + DPART + p0 + c);
    float4 b0 = *(const float4*)(dout + p1 + c);
    float4 b1 = *(const float4*)(dout + DPART + p1 + c);
    float4 d0 = *(const float4*)(db + e0 * H_DIM + c);
    float4 d1 = *(const float4*)(db + e1 * H_DIM + c);
    float4 o;
    o.x = a0.x + a1.x + b0.x + b1.x + w0 * d0.x + w1 * d1.x;
    o.y = a0.y + a1.y + b0.y + b1.y + w0 * d0.y + w1 * d1.y;
    o.z = a0.z + a1.z + b0.z + b1.z + w0 * d0.z + w1 * d1.z;
    o.w = a0.w + a1.w + b0.w + b1.w + w0 * d0.w + w1 * d1.w;
    *(float4*)(out + (size_t)t * H_DIM + c) = o;
}

// ---------------------------------------------------------------------------
extern "C" void kernel_launch(void* const* d_in, const int* in_sizes, int n_in,
                              void* d_out, int out_size, void* d_ws, size_t ws_size,
                              hipStream_t stream) {
    const float* x   = (const float*)d_in[0]; // [1,1024,1024]
    const float* rw  = (const float*)d_in[1]; // [8,1024]
    const float* rb  = (const float*)d_in[2]; // [8]
    const float* gup = (const float*)d_in[3]; // [8,1024,2048]
    const float* gub = (const float*)d_in[4]; // [8,2048]
    const float* dp  = (const float*)d_in[5]; // [8,1024,1024]
    const float* db  = (const float*)d_in[6]; // [8,1024]
    float* out = (float*)d_out;

    char* ws = (char*)d_ws;
    int*   counts   = (int*)(ws);                       // 8 ints
    int*   ebase    = (int*)(ws + 32);                  // 8 ints
    int*   tk_e     = (int*)(ws + 64);                  // 2048 ints
    int*   tk_slot  = (int*)(ws + 64 + 8192);           // 2048 ints
    float* tk_w     = (float*)(ws + 64 + 16384);        // 2048 f32
    int*   tok_list = (int*)(ws + 64 + 24576);          // 8*1024 ints
    float* w_list   = (float*)(ws + 64 + 24576 + 32768);// 8*1024 f32
    u16*   xb       = (u16*)(ws + 90368);               // 1024*1024 bf16 (2 MB)
    u16*   act      = (u16*)(ws + 90368 + 2097152);     // 2048*1024 bf16 (4 MB)
    float* dout     = (float*)(ws + 90368 + 2097152 + 4456448); // 2 x 2048*1024 f32

    k_zero<<<1, 64, 0, stream>>>(counts);
    k_router<<<T_TOK, 256, 0, stream>>>(x, rw, rb, counts, tk_e, tk_slot, tk_w,
                                        tok_list, w_list, xb);
    k_prefix<<<1, 64, 0, stream>>>(counts, ebase);
    k_gateup<<<dim3(32, 16, 8), 256, 0, stream>>>(gup, gub, counts, ebase,
                                                  tok_list, xb, act);
    k_down<<<dim3(16, 16, 16), 256, 0, stream>>>(dp, counts, ebase, w_list, act, dout);
    k_combine<<<T_TOK, 256, 0, stream>>>(dout, db, tk_e, tk_slot, tk_w, ebase, out);
}

// Round 5
// 212.031 us; speedup vs baseline: 2.0978x; 1.0332x over previous
//
#include <hip/hip_runtime.h>
#include <hip/hip_bf16.h>

// ---------------------------------------------------------------------------
// SingleLayerMoE: T=1024 tokens, H=1024, E=8 experts, I=1024, top-2 routing.
// R4: PF2 (unroll-by-2, named regs), packed-bf16 k-pair B staging (b32 LDS
//     writes, 2-way banks = free), down-GEMM fused combine via atomicAdd into
//     out (router writes weighted bias), prefix folded into GEMM blocks.
//     4 launches: zero, router, gateup, down.
// ---------------------------------------------------------------------------

typedef unsigned short u16;
typedef __attribute__((ext_vector_type(8))) __bf16 bf16x8;
typedef __attribute__((ext_vector_type(4))) float f32x4;

#define T_TOK 1024
#define H_DIM 1024
#define E_NUM 8
#define I_DIM 1024
#define ALPHA 1.702f
#define LIMIT 7.0f
#define LSTR 72   // u16 row stride (36 dw): b128 frag reads ~2-way, b32 writes 2-way = free

__device__ __forceinline__ u16 f2bf(float f) {
    unsigned u = __builtin_bit_cast(unsigned, f);
    u = (u + 0x7FFFu + ((u >> 16) & 1u)) >> 16;
    return (u16)u;
}

// pack two fp32 -> bf16x2 (RNE); HW v_cvt_pk_bf16_f32 when available
__device__ __forceinline__ unsigned pk2(float lo, float hi) {
#if defined(__has_builtin) && __has_builtin(__builtin_amdgcn_cvt_pk_bf16_f32)
    typedef __attribute__((ext_vector_type(2))) __bf16 bf16x2_t;
    bf16x2_t v = __builtin_amdgcn_cvt_pk_bf16_f32(lo, hi);
    return __builtin_bit_cast(unsigned, v);
#else
    return (unsigned)f2bf(lo) | ((unsigned)f2bf(hi) << 16);
#endif
}

__device__ __forceinline__ f32x4 mfma16(bf16x8 a, bf16x8 b, f32x4 c) {
    return __builtin_amdgcn_mfma_f32_16x16x32_bf16(a, b, c, 0, 0, 0);
}

// expert count + prefix base from counts[8] (no array -> no scratch)
__device__ __forceinline__ void expert_range(const int* counts, int e,
                                             int& cnt, int& abase) {
    int a = 0, c = 0;
#pragma unroll
    for (int i = 0; i < E_NUM; ++i) {
        int v = counts[i];
        if (i < e) a += v;
        if (i == e) c = v;
    }
    cnt = c; abase = a;
}

// --------------------------- K0: zero counters ------------------------------
__global__ void k_zero(int* counts) {
    if (threadIdx.x < E_NUM) counts[threadIdx.x] = 0;
}

// ------------- K1: router + dispatch + x->bf16 + weighted-bias out ----------
__global__ __launch_bounds__(256) void k_router(
    const float* __restrict__ x, const float* __restrict__ rw,
    const float* __restrict__ rb, const float* __restrict__ db,
    int* __restrict__ counts, int* __restrict__ tok_list,
    float* __restrict__ w_list, u16* __restrict__ xb,
    float* __restrict__ out)
{
    const int t = blockIdx.x;
    const int tid = threadIdx.x;
    const float4 xv = *(const float4*)(x + (size_t)t * H_DIM + tid * 4);

    // bf16 copy of hidden state (A operand for gate_up GEMM)
    *(uint2*)(xb + (size_t)t * H_DIM + tid * 4) =
        make_uint2(pk2(xv.x, xv.y), pk2(xv.z, xv.w));

    float p[E_NUM];
#pragma unroll
    for (int e = 0; e < E_NUM; ++e) {
        const float4 wv = *(const float4*)(rw + e * H_DIM + tid * 4);
        p[e] = xv.x * wv.x + xv.y * wv.y + xv.z * wv.z + xv.w * wv.w;
    }
#pragma unroll
    for (int off = 32; off; off >>= 1) {
#pragma unroll
        for (int e = 0; e < E_NUM; ++e) p[e] += __shfl_down(p[e], off, 64);
    }
    __shared__ float red[4][E_NUM];
    __shared__ int se[2];
    __shared__ float sw[2];
    const int lane = tid & 63, wvid = tid >> 6;
    if (lane == 0) {
#pragma unroll
        for (int e = 0; e < E_NUM; ++e) red[wvid][e] = p[e];
    }
    __syncthreads();
    if (tid == 0) {
        float lg[E_NUM];
#pragma unroll
        for (int e = 0; e < E_NUM; ++e)
            lg[e] = red[0][e] + red[1][e] + red[2][e] + red[3][e] + rb[e];
        float m1 = -1e30f, m2 = -1e30f; int i1 = 0, i2 = 0;
#pragma unroll
        for (int e = 0; e < E_NUM; ++e) {
            float l = lg[e];
            if (l > m1) { m2 = m1; i2 = i1; m1 = l; i1 = e; }
            else if (l > m2) { m2 = l; i2 = e; }
        }
        float s = 0.f;
#pragma unroll
        for (int e = 0; e < E_NUM; ++e) s += __expf(lg[e] - m1);
        const float w0 = 1.0f / s;
        const float w1 = __expf(m2 - m1) / s;
        int slot0 = atomicAdd(&counts[i1], 1);
        tok_list[i1 * T_TOK + slot0] = t;
        w_list[i1 * T_TOK + slot0] = w0;
        int slot1 = atomicAdd(&counts[i2], 1);
        tok_list[i2 * T_TOK + slot1] = t;
        w_list[i2 * T_TOK + slot1] = w1;
        se[0] = i1; se[1] = i2; sw[0] = w0; sw[1] = w1;
    }
    __syncthreads();
    // out = w0*bias[e0] + w1*bias[e1]; down-GEMM atomically accumulates on top
    const int e0 = se[0], e1 = se[1];
    const float w0 = sw[0], w1 = sw[1];
    const int c = tid * 4;
    float4 d0 = *(const float4*)(db + e0 * H_DIM + c);
    float4 d1 = *(const float4*)(db + e1 * H_DIM + c);
    float4 o;
    o.x = w0 * d0.x + w1 * d1.x;
    o.y = w0 * d0.y + w1 * d1.y;
    o.z = w0 * d0.z + w1 * d1.z;
    o.w = w0 * d0.w + w1 * d1.w;
    *(float4*)(out + (size_t)t * H_DIM + c) = o;
}

// --------------------------- K2: gate_up GEMM + GLU -------------------------
// tile 64 rows x (32 gate + 32 up), BK=64, PF2; grid (32 strips, 16 m, 8 e).
__global__ __launch_bounds__(256) void k_gateup(
    const float* __restrict__ gup, const float* __restrict__ gub,
    const int* __restrict__ counts, const int* __restrict__ tok_list,
    const u16* __restrict__ xb, u16* __restrict__ act)
{
    const int e = blockIdx.z;
    int cnt, abase;
    expert_range(counts, e, cnt, abase);
    const int m0 = blockIdx.y * 64;
    if (m0 >= cnt) return;
    const int n0 = blockIdx.x * 32;
    const int tid = threadIdx.x;

    __shared__ __align__(16) u16 As[64 * LSTR];   // 9.2 KB
    __shared__ __align__(16) u16 Bs[64 * LSTR];   // rows 0..31 gate, 32..63 up
    unsigned* Bs32 = (unsigned*)Bs;

    // A staging: row = tid>>2, k-quarter = (tid&3)*16
    const int arow_i = tid >> 2, akq = (tid & 3) * 16;
    const int aslot = m0 + arow_i;
    const int atok = (aslot < cnt) ? tok_list[e * T_TOK + aslot] : 0;
    const u16* asrc = xb + (size_t)atok * H_DIM + akq;
    u16* adst = &As[arow_i * LSTR + akq];

    // B staging: kp = tid>>3 (k-pair 2kp,2kp+1), q = tid&7 (col quad)
    const int kp = tid >> 3, q = tid & 7;
    const float* bgate = gup + ((size_t)e << 21) + n0 + q * 4;

    const int lane = tid & 63, wv = tid >> 6;
    const int fm = lane & 15, kg = lane >> 4;

    f32x4 accg[2], accu[2];
#pragma unroll
    for (int nt = 0; nt < 2; ++nt) {
        accg[nt] = (f32x4){0.f, 0.f, 0.f, 0.f};
        accu[nt] = (f32x4){0.f, 0.f, 0.f, 0.f};
    }

#define GU_LOAD(A0, A1, G0, G1, U0, U1, KB)                                    \
    {                                                                          \
        const u16* ap_ = asrc + (KB);                                          \
        A0 = *(const uint4*)(ap_);                                             \
        A1 = *(const uint4*)(ap_ + 8);                                         \
        const float* gp_ = bgate + (size_t)((KB) + 2 * kp) * 2048;             \
        G0 = *(const float4*)(gp_);                                            \
        G1 = *(const float4*)(gp_ + 2048);                                     \
        U0 = *(const float4*)(gp_ + 1024);                                     \
        U1 = *(const float4*)(gp_ + 3072);                                     \
    }
#define GU_STORE(A0, A1, G0, G1, U0, U1)                                       \
    {                                                                          \
        *(uint4*)adst       = A0;                                              \
        *(uint4*)(adst + 8) = A1;                                              \
        const float* g0_ = (const float*)&G0; const float* g1_ = (const float*)&G1; \
        const float* u0_ = (const float*)&U0; const float* u1_ = (const float*)&U1; \
        _Pragma("unroll")                                                      \
        for (int j = 0; j < 4; ++j) {                                          \
            Bs32[(q * 4 + j) * 36 + kp]        = pk2(g0_[j], g1_[j]);          \
            Bs32[(32 + q * 4 + j) * 36 + kp]   = pk2(u0_[j], u1_[j]);          \
        }                                                                      \
    }
#define GU_MFMA()                                                              \
    {                                                                          \
        _Pragma("unroll")                                                      \
        for (int sub = 0; sub < 2; ++sub) {                                    \
            bf16x8 af = *(const bf16x8*)&As[(wv * 16 + fm) * LSTR + sub * 32 + kg * 8]; \
            _Pragma("unroll")                                                  \
            for (int nt = 0; nt < 2; ++nt) {                                   \
                bf16x8 bg = *(const bf16x8*)&Bs[(nt * 16 + fm) * LSTR + sub * 32 + kg * 8]; \
                bf16x8 bu = *(const bf16x8*)&Bs[(32 + nt * 16 + fm) * LSTR + sub * 32 + kg * 8]; \
                accg[nt] = mfma16(af, bg, accg[nt]);                           \
                accu[nt] = mfma16(af, bu, accu[nt]);                           \
            }                                                                  \
        }                                                                      \
    }

    uint4 a0s0, a1s0, a0s1, a1s1;
    float4 g0s0, g1s0, u0s0, u1s0, g0s1, g1s1, u0s1, u1s1;
    GU_LOAD(a0s0, a1s0, g0s0, g1s0, u0s0, u1s0, 0);
    GU_LOAD(a0s1, a1s1, g0s1, g1s1, u0s1, u1s1, 64);

    for (int kb = 0; kb < H_DIM; kb += 128) {
        __syncthreads();
        GU_STORE(a0s0, a1s0, g0s0, g1s0, u0s0, u1s0);
        if (kb + 128 < H_DIM) GU_LOAD(a0s0, a1s0, g0s0, g1s0, u0s0, u1s0, kb + 128);
        __syncthreads();
        GU_MFMA();

        __syncthreads();
        GU_STORE(a0s1, a1s1, g0s1, g1s1, u0s1, u1s1);
        if (kb + 192 < H_DIM) GU_LOAD(a0s1, a1s1, g0s1, g1s1, u0s1, u1s1, kb + 192);
        __syncthreads();
        GU_MFMA();
    }
#undef GU_LOAD
#undef GU_STORE
#undef GU_MFMA

    // epilogue: bias + clamped GLU -> compact bf16 act rows
#pragma unroll
    for (int r = 0; r < 4; ++r) {
        int rowb = wv * 16 + kg * 4 + r;       // C/D: row=(lane>>4)*4+reg
        int slot = m0 + rowb;
        if (slot >= cnt) continue;
        size_t arow_o = (size_t)(abase + slot) * I_DIM;
#pragma unroll
        for (int nt = 0; nt < 2; ++nt) {
            int cn = n0 + nt * 16 + fm;        // C/D: col=lane&15
            float g = accg[nt][r] + gub[e * 2048 + cn];
            float u = accu[nt][r] + gub[e * 2048 + 1024 + cn];
            g = fminf(g, LIMIT);
            u = fminf(fmaxf(u, -LIMIT), LIMIT);
            float glu = g / (1.f + __expf(-ALPHA * g));
            act[arow_o + cn] = f2bf((u + 1.f) * glu);
        }
    }
}

// ---------------- K3: down GEMM * w, atomic combine into out ----------------
// tile 64 rows x 64 cols, K-split 2 (512 each), BK=64, PF2;
// grid (16 strips, 16 m, 8 e * 2 ks).
__global__ __launch_bounds__(256) void k_down(
    const float* __restrict__ dp,
    const int* __restrict__ counts, const int* __restrict__ tok_list,
    const float* __restrict__ w_list,
    const u16* __restrict__ act, float* __restrict__ out)
{
    const int e = blockIdx.z & 7, ks = blockIdx.z >> 3;
    int cnt, abase;
    expert_range(counts, e, cnt, abase);
    const int m0 = blockIdx.y * 64;
    if (m0 >= cnt) return;
    const int n0 = blockIdx.x * 64;
    const int tid = threadIdx.x;

    __shared__ __align__(16) u16 As[64 * LSTR];
    __shared__ __align__(16) u16 Bs[64 * LSTR];
    unsigned* Bs32 = (unsigned*)Bs;

    const int arow_i = tid >> 2, akq = (tid & 3) * 16;
    // rows past cnt read slack rows (finite), masked at store
    const u16* asrc = act + (size_t)(abase + m0 + arow_i) * I_DIM + ks * 512 + akq;
    u16* adst = &As[arow_i * LSTR + akq];

    const int kp = tid >> 3, q = tid & 7;     // cols 4q..4q+3 and 32+4q..
    const float* bsrc = dp + ((size_t)e << 20) + (size_t)(ks * 512) * 1024 + n0 + q * 4;

    const int lane = tid & 63, wv = tid >> 6;
    const int fm = lane & 15, kg = lane >> 4;

    f32x4 acc[4];
#pragma unroll
    for (int nt = 0; nt < 4; ++nt) acc[nt] = (f32x4){0.f, 0.f, 0.f, 0.f};

#define DN_LOAD(A0, A1, B00, B01, B10, B11, KB)                                \
    {                                                                          \
        const u16* ap_ = asrc + (KB);                                          \
        A0 = *(const uint4*)(ap_);                                             \
        A1 = *(const uint4*)(ap_ + 8);                                         \
        const float* bp_ = bsrc + (size_t)((KB) + 2 * kp) * 1024;              \
        B00 = *(const float4*)(bp_);                                           \
        B01 = *(const float4*)(bp_ + 1024);                                    \
        B10 = *(const float4*)(bp_ + 32);                                      \
        B11 = *(const float4*)(bp_ + 1056);                                    \
    }
#define DN_STORE(A0, A1, B00, B01, B10, B11)                                   \
    {                                                                          \
        *(uint4*)adst       = A0;                                              \
        *(uint4*)(adst + 8) = A1;                                              \
        const float* b00_ = (const float*)&B00; const float* b01_ = (const float*)&B01; \
        const float* b10_ = (const float*)&B10; const float* b11_ = (const float*)&B11; \
        _Pragma("unroll")                                                      \
        for (int j = 0; j < 4; ++j) {                                          \
            Bs32[(q * 4 + j) * 36 + kp]      = pk2(b00_[j], b01_[j]);          \
            Bs32[(32 + q * 4 + j) * 36 + kp] = pk2(b10_[j], b11_[j]);          \
        }                                                                      \
    }
#define DN_MFMA()                                                              \
    {                                                                          \
        _Pragma("unroll")                                                      \
        for (int sub = 0; sub < 2; ++sub) {                                    \
            bf16x8 af = *(const bf16x8*)&As[(wv * 16 + fm) * LSTR + sub * 32 + kg * 8]; \
            _Pragma("unroll")                                                  \
            for (int nt = 0; nt < 4; ++nt) {                                   \
                bf16x8 b = *(const bf16x8*)&Bs[(nt * 16 + fm) * LSTR + sub * 32 + kg * 8]; \
                acc[nt] = mfma16(af, b, acc[nt]);                              \
            }                                                                  \
        }                                                                      \
    }

    uint4 a0s0, a1s0, a0s1, a1s1;
    float4 b00s0, b01s0, b10s0, b11s0, b00s1, b01s1, b10s1, b11s1;
    DN_LOAD(a0s0, a1s0, b00s0, b01s0, b10s0, b11s0, 0);
    DN_LOAD(a0s1, a1s1, b00s1, b01s1, b10s1, b11s1, 64);

    for (int kb = 0; kb < 512; kb += 128) {
        __syncthreads();
        DN_STORE(a0s0, a1s0, b00s0, b01s0, b10s0, b11s0);
        if (kb + 128 < 512) DN_LOAD(a0s0, a1s0, b00s0, b01s0, b10s0, b11s0, kb + 128);
        __syncthreads();
        DN_MFMA();

        __syncthreads();
        DN_STORE(a0s1, a1s1, b00s1, b01s1, b10s1, b11s1);
        if (kb + 192 < 512) DN_LOAD(a0s1, a1s1, b00s1, b01s1, b10s1, b11s1, kb + 192);
        __syncthreads();
        DN_MFMA();
    }
#undef DN_LOAD
#undef DN_STORE
#undef DN_MFMA

#pragma unroll
    for (int r = 0; r < 4; ++r) {
        int rowb = wv * 16 + kg * 4 + r;
        int slot = m0 + rowb;
        if (slot >= cnt) continue;
        float wgt = w_list[e * T_TOK + slot];
        int tok = tok_list[e * T_TOK + slot];
        float* orow = out + (size_t)tok * H_DIM + n0;
#pragma unroll
        for (int nt = 0; nt < 4; ++nt)
            atomicAdd(orow + nt * 16 + fm, acc[nt][r] * wgt);
    }
}

// ---------------------------------------------------------------------------
extern "C" void kernel_launch(void* const* d_in, const int* in_sizes, int n_in,
                              void* d_out, int out_size, void* d_ws, size_t ws_size,
                              hipStream_t stream) {
    const float* x   = (const float*)d_in[0]; // [1,1024,1024]
    const float* rw  = (const float*)d_in[1]; // [8,1024]
    const float* rb  = (const float*)d_in[2]; // [8]
    const float* gup = (const float*)d_in[3]; // [8,1024,2048]
    const float* gub = (const float*)d_in[4]; // [8,2048]
    const float* dp  = (const float*)d_in[5]; // [8,1024,1024]
    const float* db  = (const float*)d_in[6]; // [8,1024]
    float* out = (float*)d_out;

    char* ws = (char*)d_ws;
    int*   counts   = (int*)(ws);                    // 8 ints
    int*   tok_list = (int*)(ws + 64);               // 8*1024 ints (32 KB)
    float* w_list   = (float*)(ws + 64 + 32768);     // 8*1024 f32  (32 KB)
    u16*   xb       = (u16*)(ws + 65600);            // 1024*1024 bf16 (2 MB)
    u16*   act      = (u16*)(ws + 65600 + 2097152);  // 2112*1024 bf16 (4.125 MB + slack)

    k_zero<<<1, 64, 0, stream>>>(counts);
    k_router<<<T_TOK, 256, 0, stream>>>(x, rw, rb, db, counts, tok_list, w_list,
                                        xb, out);
    k_gateup<<<dim3(32, 16, 8), 256, 0, stream>>>(gup, gub, counts, tok_list,
                                                  xb, act);
    k_down<<<dim3(16, 16, 16), 256, 0, stream>>>(dp, counts, tok_list, w_list,
                                                 act, out);
}